// Round 1
// baseline (42.933 us; speedup 1.0000x reference)
//
#include <hip/hip_runtime.h>
#include <math.h>

#define DIMD 16
#define HIDN 32
#define NN   256
#define MM   256
#define DIAG_MIN 0.316f
#define DIAG_MAX 3.16f

// One thread per output element (b, n, m).
// block = 256 threads (all m for one (b,n)); grid = B*N = 512 blocks.
// x1/W1/b1/W2/b2 addresses are wave-uniform -> scalar loads via sL1.
// dist_sq = dx^T (L L^T) dx = ||L^T dx||^2 ; only lower-tri L entries needed.
__global__ __launch_bounds__(256) void rm_kernel(
    const float* __restrict__ x1, const float* __restrict__ x2,
    const float* __restrict__ W1, const float* __restrict__ b1,
    const float* __restrict__ W2, const float* __restrict__ b2,
    float* __restrict__ out)
{
    // dx staged in LDS so the runtime-i loop can index it without scratch.
    // Layout [i][tid]: consecutive lanes -> consecutive banks, conflict-free.
    __shared__ float dxs[DIMD * 256];

    const int tid = threadIdx.x;      // m
    const int bn  = blockIdx.x;       // b*N + n
    const int b   = bn >> 8;

    const float4* a4 = reinterpret_cast<const float4*>(x1 + bn * DIMD);
    const float4* b4 = reinterpret_cast<const float4*>(x2 + (b * MM + tid) * DIMD);

    float mid[DIMD];
    #pragma unroll
    for (int q = 0; q < 4; ++q) {
        float4 va = a4[q];
        float4 vb = b4[q];
        mid[4*q+0] = (va.x + vb.x) * 0.5f;
        mid[4*q+1] = (va.y + vb.y) * 0.5f;
        mid[4*q+2] = (va.z + vb.z) * 0.5f;
        mid[4*q+3] = (va.w + vb.w) * 0.5f;
        dxs[(4*q+0)*256 + tid] = vb.x - va.x;
        dxs[(4*q+1)*256 + tid] = vb.y - va.y;
        dxs[(4*q+2)*256 + tid] = vb.z - va.z;
        dxs[(4*q+3)*256 + tid] = vb.w - va.w;
    }

    // Layer 1: h = silu(mid @ W1^T + b1), fully static -> registers.
    float h[HIDN];
    #pragma unroll
    for (int j = 0; j < HIDN; ++j) {
        float acc = b1[j];
        #pragma unroll
        for (int i = 0; i < DIMD; ++i)
            acc = fmaf(mid[i], W1[j * DIMD + i], acc);
        // silu(x) = x / (1 + exp(-x))
        h[j] = __fdividef(acc, 1.0f + __expf(-acc));
    }

    float y[DIMD];
    #pragma unroll
    for (int k = 0; k < DIMD; ++k) y[k] = 0.0f;

    // y_k = sum_{i>=k} dx_i * L[i][k];  L[i][k] = raw[i*16+k] for i>k,
    // diag: clamp(softplus(raw[k*17]+1), DIAG_MIN, DIAG_MAX).
    #pragma unroll 1
    for (int i = 0; i < DIMD; ++i) {
        const float dxi = dxs[i * 256 + tid];
        const int rowbase = i * DIMD;
        #pragma unroll
        for (int k = 0; k < DIMD; ++k) {
            if (k <= i) {                       // uniform guard: s_cbranch
                const float* w = W2 + (rowbase + k) * HIDN;
                float r = b2[rowbase + k];
                #pragma unroll
                for (int j = 0; j < HIDN; ++j)
                    r = fmaf(h[j], w[j], r);    // w[j] is wave-uniform -> SGPR
                if (k == i) {                   // diagonal element
                    r += 1.0f;                  // + I bias
                    float sp = fmaxf(r, 0.0f) + log1pf(__expf(-fabsf(r)));
                    r = fminf(fmaxf(sp, DIAG_MIN), DIAG_MAX);
                }
                y[k] = fmaf(dxi, r, y[k]);
            }
        }
    }

    float dist = 0.0f;
    #pragma unroll
    for (int k = 0; k < DIMD; ++k)
        dist = fmaf(y[k], y[k], dist);

    out[bn * MM + tid] = sqrtf(fmaxf(dist, 1e-6f));
}

extern "C" void kernel_launch(void* const* d_in, const int* in_sizes, int n_in,
                              void* d_out, int out_size, void* d_ws, size_t ws_size,
                              hipStream_t stream) {
    const float* x1 = (const float*)d_in[0];
    const float* x2 = (const float*)d_in[1];
    const float* W1 = (const float*)d_in[2];
    const float* b1 = (const float*)d_in[3];
    const float* W2 = (const float*)d_in[4];
    const float* b2 = (const float*)d_in[5];
    float* out = (float*)d_out;

    const int BN = 2 * NN;  // B * N = 512 blocks
    rm_kernel<<<BN, 256, 0, stream>>>(x1, x2, W1, b1, W2, b2, out);
}

// Round 2
// 41.415 us; speedup vs baseline: 1.0367x; 1.0367x over previous
//
#include <hip/hip_runtime.h>
#include <math.h>

#define DIMD 16
#define HIDN 32
#define NN   256
#define MM   256
#define DIAG_MIN 0.316f
#define DIAG_MAX 3.16f

// 4-way column split across the 4 waves of a 256-thread block.
// Block covers 64 outputs (one m-chunk of one (b,n)); wave w handles
// L-columns {w, 7-w, 8+w, 15-w} (34 rows each, balanced).
// Total threads = 4 * 131072 -> 8192 waves -> 8 waves/SIMD (100% cap).
// k is wave-uniform (readfirstlane) -> W2/b2 rows come in as scalar loads.
__global__ __launch_bounds__(256, 8) void rm_kernel(
    const float* __restrict__ x1, const float* __restrict__ x2,
    const float* __restrict__ W1, const float* __restrict__ b1,
    const float* __restrict__ W2, const float* __restrict__ b2,
    float* __restrict__ out)
{
    __shared__ float dxs[DIMD * 64];   // dx shared by all 4 waves, [i][lane]
    __shared__ float part[4][64];      // per-wave dist^2 partials

    const int tid  = threadIdx.x;
    const int lane = tid & 63;
    const int wid  = __builtin_amdgcn_readfirstlane(tid >> 6);  // column set

    const int blk = blockIdx.x;        // 0..2047
    const int mc  = blk & 3;           // m-chunk (64 outputs each)
    const int bn  = blk >> 2;          // b*N + n
    const int b   = bn >> 8;
    const int m   = mc * 64 + lane;

    const float4* a4 = reinterpret_cast<const float4*>(x1 + bn * DIMD);
    const float4* c4 = reinterpret_cast<const float4*>(x2 + (b * MM + m) * DIMD);

    float mid[DIMD];
    #pragma unroll
    for (int q = 0; q < 4; ++q) {
        float4 va = a4[q];
        float4 vb = c4[q];
        mid[4*q+0] = (va.x + vb.x) * 0.5f;
        mid[4*q+1] = (va.y + vb.y) * 0.5f;
        mid[4*q+2] = (va.z + vb.z) * 0.5f;
        mid[4*q+3] = (va.w + vb.w) * 0.5f;
        if (wid == 0) {
            dxs[(4*q+0)*64 + lane] = vb.x - va.x;
            dxs[(4*q+1)*64 + lane] = vb.y - va.y;
            dxs[(4*q+2)*64 + lane] = vb.z - va.z;
            dxs[(4*q+3)*64 + lane] = vb.w - va.w;
        }
    }

    // Layer 1: h = silu(mid @ W1^T + b1) — static, stays in registers.
    float h[HIDN];
    #pragma unroll
    for (int j = 0; j < HIDN; ++j) {
        float a0 = b1[j], a1 = 0.0f;
        #pragma unroll
        for (int i = 0; i < DIMD; i += 2) {
            a0 = fmaf(mid[i],     W1[j * DIMD + i],     a0);
            a1 = fmaf(mid[i + 1], W1[j * DIMD + i + 1], a1);
        }
        float acc = a0 + a1;
        h[j] = __fdividef(acc, 1.0f + __expf(-acc));
    }

    __syncthreads();  // dxs ready

    float distp = 0.0f;

    // This wave's 4 columns: {wid, 7-wid, 8+wid, 15-wid}.
    #pragma unroll
    for (int kk = 0; kk < 4; ++kk) {
        int kv;
        switch (kk) {
            case 0:  kv = wid;      break;
            case 1:  kv = 7 - wid;  break;
            case 2:  kv = 8 + wid;  break;
            default: kv = 15 - wid; break;
        }
        const int k = __builtin_amdgcn_readfirstlane(kv);

        // Peeled diagonal row i == k.
        float yk;
        {
            const float* w2r = W2 + (k * DIMD + k) * HIDN;
            float r0 = b2[k * DIMD + k], r1 = 0.0f;
            #pragma unroll
            for (int j = 0; j < HIDN; j += 2) {
                r0 = fmaf(h[j],     w2r[j],     r0);
                r1 = fmaf(h[j + 1], w2r[j + 1], r1);
            }
            float r = r0 + r1 + 1.0f;  // + identity bias
            float sp = fmaxf(r, 0.0f) + log1pf(__expf(-fabsf(r)));
            r = fminf(fmaxf(sp, DIAG_MIN), DIAG_MAX);
            yk = dxs[k * 64 + lane] * r;
        }

        // Off-diagonal rows i = k+1 .. 15 (uniform trip count).
        #pragma unroll 1
        for (int i = k + 1; i < DIMD; ++i) {
            const float* w2r = W2 + (i * DIMD + k) * HIDN;
            float r0 = b2[i * DIMD + k], r1 = 0.0f;
            #pragma unroll
            for (int j = 0; j < HIDN; j += 2) {
                r0 = fmaf(h[j],     w2r[j],     r0);
                r1 = fmaf(h[j + 1], w2r[j + 1], r1);
            }
            yk = fmaf(dxs[i * 64 + lane], r0 + r1, yk);
        }

        distp = fmaf(yk, yk, distp);
    }

    part[wid][lane] = distp;
    __syncthreads();

    if (wid == 0) {
        float d = part[0][lane] + part[1][lane] + part[2][lane] + part[3][lane];
        out[bn * MM + m] = sqrtf(fmaxf(d, 1e-6f));
    }
}

extern "C" void kernel_launch(void* const* d_in, const int* in_sizes, int n_in,
                              void* d_out, int out_size, void* d_ws, size_t ws_size,
                              hipStream_t stream) {
    const float* x1 = (const float*)d_in[0];
    const float* x2 = (const float*)d_in[1];
    const float* W1 = (const float*)d_in[2];
    const float* b1 = (const float*)d_in[3];
    const float* W2 = (const float*)d_in[4];
    const float* b2 = (const float*)d_in[5];
    float* out = (float*)d_out;

    const int nblocks = 2 * NN * (MM / 64);  // 2048
    rm_kernel<<<nblocks, 256, 0, stream>>>(x1, x2, W1, b1, W2, b2, out);
}

// Round 3
// 28.895 us; speedup vs baseline: 1.4858x; 1.4333x over previous
//
#include <hip/hip_runtime.h>
#include <math.h>

#define DIMD 16
#define HIDN 32
#define NN   256
#define MM   256
#define DIAG_MIN 0.316f
#define DIAG_MAX 3.16f

// Block = 256 threads = 4 waves, covers 64 outputs (one m-chunk of one (b,n)).
// Wave w owns L-columns {w, 7-w, 8+w, 15-w} (34 rows each, balanced: 30 off-diag + 4 diag).
// Layer 1 is split across waves (wave w computes h[8w..8w+8) for all 64 outputs)
// and shared via LDS — no x4 recompute.
// launch_bounds(256,4): VGPR cap 128 — R1's (256,8) forced 32 VGPRs and spilled
// ~25 MB of scratch traffic (WRITE_SIZE 512KB->21MB). Demand is ~60 regs.
__global__ __launch_bounds__(256, 4) void rm_kernel(
    const float* __restrict__ x1, const float* __restrict__ x2,
    const float* __restrict__ W1, const float* __restrict__ b1,
    const float* __restrict__ W2, const float* __restrict__ b2,
    float* __restrict__ out)
{
    __shared__ float dxs[DIMD * 64];    // dx, [i][lane]
    __shared__ float hls[HIDN * 64];    // hidden activations, [j][lane]
    __shared__ float part[4][64];       // per-wave dist^2 partials

    const int tid  = threadIdx.x;
    const int lane = tid & 63;
    const int wid  = __builtin_amdgcn_readfirstlane(tid >> 6);

    const int blk = blockIdx.x;         // 0..2047
    const int mc  = blk & 3;            // m-chunk
    const int bn  = blk >> 2;           // b*N + n
    const int b   = bn >> 8;
    const int m   = mc * 64 + lane;

    const float4* a4 = reinterpret_cast<const float4*>(x1 + bn * DIMD);
    const float4* c4 = reinterpret_cast<const float4*>(x2 + (b * MM + m) * DIMD);

    float mid[DIMD];
    #pragma unroll
    for (int q = 0; q < 4; ++q) {
        float4 va = a4[q];
        float4 vb = c4[q];
        mid[4*q+0] = (va.x + vb.x) * 0.5f;
        mid[4*q+1] = (va.y + vb.y) * 0.5f;
        mid[4*q+2] = (va.z + vb.z) * 0.5f;
        mid[4*q+3] = (va.w + vb.w) * 0.5f;
        if (wid == 0) {
            dxs[(4*q+0)*64 + lane] = vb.x - va.x;
            dxs[(4*q+1)*64 + lane] = vb.y - va.y;
            dxs[(4*q+2)*64 + lane] = vb.z - va.z;
            dxs[(4*q+3)*64 + lane] = vb.w - va.w;
        }
    }

    // Layer 1, split across waves: this wave computes h[8*wid .. 8*wid+8).
    #pragma unroll
    for (int jo = 0; jo < 8; ++jo) {
        const int j = wid * 8 + jo;
        float a0 = b1[j], a1 = 0.0f;
        #pragma unroll
        for (int i = 0; i < DIMD; i += 2) {
            a0 = fmaf(mid[i],     W1[j * DIMD + i],     a0);
            a1 = fmaf(mid[i + 1], W1[j * DIMD + i + 1], a1);
        }
        float acc = a0 + a1;
        hls[j * 64 + lane] = __fdividef(acc, 1.0f + __expf(-acc));  // silu
    }

    __syncthreads();  // dxs + hls ready

    // Pull this output's hidden vector into registers ([j][lane]: conflict-free).
    float h[HIDN];
    #pragma unroll
    for (int j = 0; j < HIDN; ++j)
        h[j] = hls[j * 64 + lane];

    float distp = 0.0f;

    #pragma unroll
    for (int kk = 0; kk < 4; ++kk) {
        int kv;
        switch (kk) {
            case 0:  kv = wid;      break;
            case 1:  kv = 7 - wid;  break;
            case 2:  kv = 8 + wid;  break;
            default: kv = 15 - wid; break;
        }
        const int k = __builtin_amdgcn_readfirstlane(kv);

        // Diagonal row i == k: softplus + clamp.
        float yk;
        {
            const float* w2r = W2 + (k * DIMD + k) * HIDN;
            float r0 = b2[k * DIMD + k], r1 = 0.0f;
            #pragma unroll
            for (int j = 0; j < HIDN; j += 2) {
                r0 = fmaf(h[j],     w2r[j],     r0);
                r1 = fmaf(h[j + 1], w2r[j + 1], r1);
            }
            float r = r0 + r1 + 1.0f;  // + identity bias
            float sp = fmaxf(r, 0.0f) + log1pf(__expf(-fabsf(r)));
            r = fminf(fmaxf(sp, DIAG_MIN), DIAG_MAX);
            yk = dxs[k * 64 + lane] * r;
        }

        // Off-diagonal rows i = k+1 .. 15 (wave-uniform trip count).
        #pragma unroll 1
        for (int i = k + 1; i < DIMD; ++i) {
            const float* w2r = W2 + (i * DIMD + k) * HIDN;
            float r0 = b2[i * DIMD + k], r1 = 0.0f;
            #pragma unroll
            for (int j = 0; j < HIDN; j += 2) {
                r0 = fmaf(h[j],     w2r[j],     r0);
                r1 = fmaf(h[j + 1], w2r[j + 1], r1);
            }
            yk = fmaf(dxs[i * 64 + lane], r0 + r1, yk);
        }

        distp = fmaf(yk, yk, distp);
    }

    part[wid][lane] = distp;
    __syncthreads();

    if (wid == 0) {
        float d = part[0][lane] + part[1][lane] + part[2][lane] + part[3][lane];
        out[bn * MM + m] = sqrtf(fmaxf(d, 1e-6f));
    }
}

extern "C" void kernel_launch(void* const* d_in, const int* in_sizes, int n_in,
                              void* d_out, int out_size, void* d_ws, size_t ws_size,
                              hipStream_t stream) {
    const float* x1 = (const float*)d_in[0];
    const float* x2 = (const float*)d_in[1];
    const float* W1 = (const float*)d_in[2];
    const float* b1 = (const float*)d_in[3];
    const float* W2 = (const float*)d_in[4];
    const float* b2 = (const float*)d_in[5];
    float* out = (float*)d_out;

    const int nblocks = 2 * NN * (MM / 64);  // 2048
    rm_kernel<<<nblocks, 256, 0, stream>>>(x1, x2, W1, b1, W2, b2, out);
}